// Round 2
// baseline (919.079 us; speedup 1.0000x reference)
//
#include <hip/hip_runtime.h>
#include <math.h>

#define B_ 2
#define C_ 36
#define H_ 512
#define W_ 512
#define K_ 9
#define HW_ (H_ * W_)
#define ROWF4 (W_ * C_ / 4)  // float4 pitch of one image row in featT = 4608

// ---------------------------------------------------------------------------
// Transpose features [B,C,H,W] -> [B,H,W,C].  (unchanged, known-good)
// ---------------------------------------------------------------------------
__global__ __launch_bounds__(256) void transpose_kernel(const float* __restrict__ in,
                                                        float* __restrict__ out) {
  __shared__ float tile[64][37];
  int blk = blockIdx.x;  // ((b*H + h)*8 + wt)
  int wt = blk & 7;
  int h = (blk >> 3) & (H_ - 1);
  int b = blk >> 12;
  int w0 = wt << 6;
  int tid = threadIdx.x;
  const float* src = in + ((size_t)b * C_) * HW_ + (size_t)h * W_ + w0;
#pragma unroll
  for (int it = 0; it < 9; ++it) {
    int idx = it * 256 + tid;
    int c = idx >> 6;
    int wl = idx & 63;
    tile[wl][c] = src[(size_t)c * HW_ + wl];
  }
  __syncthreads();
  float* dst = out + (((size_t)b * H_ + h) * W_ + w0) * C_;
#pragma unroll
  for (int it = 0; it < 9; ++it) {
    int idx = it * 256 + tid;
    int wl = idx / 36;
    int c = idx - wl * 36;
    dst[idx] = tile[wl][c];
  }
}

// ---------------------------------------------------------------------------
// Thread-per-pixel eval on pixel-major featT.
// v5: the cooperative-wave structure (v4) was latency-bound: 1-wave blocks at
// ~20% occupancy, barrier-serialized LDS round trips, and half-wave-idle owner
// reduces.  Thread-per-pixel needs no LDS, no barriers, no masked phases:
// per px*k it is exactly 36 dwordx4 gathers + 36*4 bilinear FMA + 108 abs-diff
// accumulates, all full-lane.  256-thread blocks + VGPR<=128 give 4 waves/SIMD
// of schedulable parallelism; the 36 independent loads per k provide ILP.
// Block->pixel mapping keeps the 8-region (2b x 4 quadrant) XCD round-robin so
// gather windows stay L2/L3-local, matching v4's locality.
// ---------------------------------------------------------------------------
__global__ __launch_bounds__(256, 4) void eval_kernel_tp(const float* __restrict__ feat,
                                                         const float* __restrict__ offx,
                                                         const float* __restrict__ offy,
                                                         float* __restrict__ out) {
  int tid = threadIdx.x;
  int blk = blockIdx.x;
  int region = blk & 7;   // XCD round-robin residue -> fixed 256x256 region
  int slot = blk >> 3;    // 0..255 : row within the quadrant
  int b = region >> 2;
  int qd = region & 3;
  int h = ((qd >> 1) << 8) + slot;
  int w = ((qd & 1) << 8) + tid;
  int ph = h * W_ + w;
  int p = b * HW_ + ph;

  const float4* feat4 = reinterpret_cast<const float4*>(feat);

  // all 9 candidates' offsets up front (independent, coalesced loads)
  const float* oxb = offx + (size_t)b * K_ * HW_ + ph;
  const float* oyb = offy + (size_t)b * K_ * HW_ + ph;
  float oxv[K_], oyv[K_];
#pragma unroll
  for (int k = 0; k < K_; ++k) {
    oxv[k] = oxb[k * HW_];
    oyv[k] = oyb[k * HW_];
  }

  // own pixel's 36 center features -> registers (contiguous, 16B aligned)
  float F[C_];
  {
    const float4* myF = feat4 + (size_t)p * 9;
#pragma unroll
    for (int i = 0; i < 9; ++i) {
      float4 v = myF[i];
      F[4 * i + 0] = v.x; F[4 * i + 1] = v.y; F[4 * i + 2] = v.z; F[4 * i + 3] = v.w;
    }
  }

  float lx = (float)w;
  float ly = (float)h;

  float M = -INFINITY, den = 0.f, axs = 0.f, ays = 0.f;

#pragma unroll 1
  for (int k = 0; k < K_; ++k) {
    float ox = oxv[k];
    float oy = oyv[k];
    float rx = fminf(fmaxf(lx + ox, 0.0f), 511.0f);
    float ry = fminf(fmaxf(ly + oy, 0.0f), 511.0f);
    float gx = (rx - 255.5f) / 255.5f;
    float gy = (ry - 255.5f) / 255.5f;
    float px = (gx + 1.0f) * 0.5f * 511.0f;
    float py = (gy + 1.0f) * 0.5f * 511.0f;
    int x0 = (int)floorf(px); x0 = (x0 > 510) ? 510 : x0;
    int y0 = (int)floorf(py); y0 = (y0 > 510) ? 510 : y0;
    float wx = px - (float)x0;
    float wy = py - (float)y0;
    float w00 = (1.0f - wx) * (1.0f - wy);
    float w01 = wx * (1.0f - wy);
    float w10 = (1.0f - wx) * wy;
    float w11 = wx * wy;

    // float4 base of the (y0, x0..x0+1) run; row1 is +ROWF4 (x0<=510, y0<=510)
    const float4* r0 = feat4 + (size_t)(((b * H_ + y0) * W_ + x0) * 9);

    float D[9] = {0.f, 0.f, 0.f, 0.f, 0.f, 0.f, 0.f, 0.f, 0.f};
#pragma unroll
    for (int q = 0; q < 9; ++q) {
      float4 v00 = r0[q];
      float4 v01 = r0[9 + q];
      float4 v10 = r0[ROWF4 + q];
      float4 v11 = r0[ROWF4 + 9 + q];
      float a0 = w00 * v00.x + w01 * v01.x + w10 * v10.x + w11 * v11.x;
      float a1 = w00 * v00.y + w01 * v01.y + w10 * v10.y + w11 * v11.y;
      float a2 = w00 * v00.z + w01 * v01.z + w10 * v10.z + w11 * v11.z;
      float a3 = w00 * v00.w + w01 * v01.w + w10 * v10.w + w11 * v11.w;
      int ga = q / 3;
      int f0 = 4 * (q % 3);
      D[ga]     += fabsf(F[f0 + 0]      - a0);
      D[3 + ga] += fabsf(F[12 + f0 + 0] - a0);
      D[6 + ga] += fabsf(F[24 + f0 + 0] - a0);
      D[ga]     += fabsf(F[f0 + 1]      - a1);
      D[3 + ga] += fabsf(F[12 + f0 + 1] - a1);
      D[6 + ga] += fabsf(F[24 + f0 + 1] - a1);
      D[ga]     += fabsf(F[f0 + 2]      - a2);
      D[3 + ga] += fabsf(F[12 + f0 + 2] - a2);
      D[6 + ga] += fabsf(F[24 + f0 + 2] - a2);
      D[ga]     += fabsf(F[f0 + 3]      - a3);
      D[3 + ga] += fabsf(F[12 + f0 + 3] - a3);
      D[6 + ga] += fabsf(F[24 + f0 + 3] - a3);
    }

    float mn = D[0];
#pragma unroll
    for (int j = 1; j < 9; ++j) mn = fminf(mn, D[j]);
    float xk = -(mn / 12.0f) * 1000.0f;
    float nm = fmaxf(M, xk);
    float scl = expf(M - nm);
    float ek = expf(xk - nm);
    den = den * scl + ek;
    axs = axs * scl + ox * ek;
    ays = ays * scl + oy * ek;
    M = nm;
  }

  float resx = axs / den;
  float resy = ays / den;
  out[p] = fminf(fmaxf(resx + lx, 0.0f), 511.0f) - lx;
  out[B_ * HW_ + p] = fminf(fmaxf(resy + ly, 0.0f), 511.0f) - ly;
}

// Fallback (no scratch): original channel-major layout, thread-per-pixel.
__global__ __launch_bounds__(256) void eval_kernel_n(const float* __restrict__ feat,
                                                     const float* __restrict__ offx,
                                                     const float* __restrict__ offy,
                                                     float* __restrict__ out) {
  int p = blockIdx.x * 256 + threadIdx.x;
  int ph = p & (HW_ - 1);
  int b = p >> 18;
  float F[C_];
  const float* fb = feat + (size_t)b * C_ * HW_ + ph;
#pragma unroll
  for (int c = 0; c < C_; ++c) F[c] = fb[(size_t)c * HW_];
  float lx = (float)(ph & (W_ - 1));
  float ly = (float)((ph >> 9) & (H_ - 1));
  const float* oxb = offx + (size_t)b * K_ * HW_ + ph;
  const float* oyb = offy + (size_t)b * K_ * HW_ + ph;
  float M = -INFINITY, den = 0.f, ax = 0.f, ay = 0.f;
#pragma unroll 1
  for (int k = 0; k < K_; ++k) {
    float ox = oxb[k * HW_];
    float oy = oyb[k * HW_];
    float rx = fminf(fmaxf(lx + ox, 0.0f), 511.0f);
    float ry = fminf(fmaxf(ly + oy, 0.0f), 511.0f);
    float gx = (rx - 255.5f) / 255.5f;
    float gy = (ry - 255.5f) / 255.5f;
    float px = (gx + 1.0f) * 0.5f * 511.0f;
    float py = (gy + 1.0f) * 0.5f * 511.0f;
    int x0 = (int)floorf(px); x0 = (x0 > 510) ? 510 : x0;
    int y0 = (int)floorf(py); y0 = (y0 > 510) ? 510 : y0;
    float wx = px - (float)x0;
    float wy = py - (float)y0;
    float w00 = (1.0f - wx) * (1.0f - wy);
    float w01 = wx * (1.0f - wy);
    float w10 = (1.0f - wx) * wy;
    float w11 = wx * wy;
    float D[9] = {0.f, 0.f, 0.f, 0.f, 0.f, 0.f, 0.f, 0.f, 0.f};
    const float* pl = feat + (size_t)b * C_ * HW_ + (size_t)y0 * W_ + x0;
#pragma unroll
    for (int c = 0; c < C_; ++c) {
      const float* q0 = pl + (size_t)c * HW_;
      float v00 = q0[0], v01 = q0[1];
      float v10 = q0[W_], v11 = q0[W_ + 1];
      float a = v00 * w00 + v01 * w01 + v10 * w10 + v11 * w11;
      int i = c % 12;
      int ga = c / 12;
      D[ga]     += fabsf(F[i]      - a);
      D[3 + ga] += fabsf(F[12 + i] - a);
      D[6 + ga] += fabsf(F[24 + i] - a);
    }
    float mn = D[0];
#pragma unroll
    for (int j = 1; j < 9; ++j) mn = fminf(mn, D[j]);
    float xk = -(mn / 12.0f) * 1000.0f;
    float nm = fmaxf(M, xk);
    float sc = expf(M - nm);
    float ek = expf(xk - nm);
    den = den * sc + ek;
    ax = ax * sc + ox * ek;
    ay = ay * sc + oy * ek;
    M = nm;
  }
  float resx = ax / den;
  float resy = ay / den;
  out[p] = fminf(fmaxf(resx + lx, 0.0f), 511.0f) - lx;
  out[B_ * HW_ + p] = fminf(fmaxf(resy + ly, 0.0f), 511.0f) - ly;
}

extern "C" void kernel_launch(void* const* d_in, const int* in_sizes, int n_in,
                              void* d_out, int out_size, void* d_ws, size_t ws_size,
                              hipStream_t stream) {
  const float* features = (const float*)d_in[0];
  const float* offset_x = (const float*)d_in[1];
  const float* offset_y = (const float*)d_in[2];
  float* out = (float*)d_out;

  const int npix = B_ * HW_;  // 524288
  const size_t need = (size_t)npix * C_ * sizeof(float);  // 75.5 MB

  if (ws_size >= need) {
    float* featT = (float*)d_ws;
    transpose_kernel<<<B_ * H_ * (W_ / 64), 256, 0, stream>>>(features, featT);
    eval_kernel_tp<<<npix / 256, 256, 0, stream>>>(featT, offset_x, offset_y, out);
  } else {
    eval_kernel_n<<<npix / 256, 256, 0, stream>>>(features, offset_x, offset_y, out);
  }
}

// Round 3
// 510.509 us; speedup vs baseline: 1.8003x; 1.8003x over previous
//
#include <hip/hip_runtime.h>
#include <math.h>

#define B_ 2
#define C_ 36
#define H_ 512
#define W_ 512
#define K_ 9
#define HW_ (H_ * W_)
#define ROWF4 (W_ * C_ / 4)  // float4 pitch of one image row in featT = 4608

// ---------------------------------------------------------------------------
// Transpose features [B,C,H,W] -> [B,H,W,C].  (unchanged, known-good)
// ---------------------------------------------------------------------------
__global__ __launch_bounds__(256) void transpose_kernel(const float* __restrict__ in,
                                                        float* __restrict__ out) {
  __shared__ float tile[64][37];
  int blk = blockIdx.x;  // ((b*H + h)*8 + wt)
  int wt = blk & 7;
  int h = (blk >> 3) & (H_ - 1);
  int b = blk >> 12;
  int w0 = wt << 6;
  int tid = threadIdx.x;
  const float* src = in + ((size_t)b * C_) * HW_ + (size_t)h * W_ + w0;
#pragma unroll
  for (int it = 0; it < 9; ++it) {
    int idx = it * 256 + tid;
    int c = idx >> 6;
    int wl = idx & 63;
    tile[wl][c] = src[(size_t)c * HW_ + wl];
  }
  __syncthreads();
  float* dst = out + (((size_t)b * H_ + h) * W_ + w0) * C_;
#pragma unroll
  for (int it = 0; it < 9; ++it) {
    int idx = it * 256 + tid;
    int wl = idx / 36;
    int c = idx - wl * 36;
    dst[idx] = tile[wl][c];
  }
}

// ---------------------------------------------------------------------------
// v6: v4's geometry + residency, v5's thread-per-pixel body.
// Lesson from v5: the gather demand (2.7 GB vs 75 MB featT) is only viable at
// ~94% L2 hit, which requires the resident gather front to stay a ~50-row band
// per XCD (v4: ~6.5 waves/CU x 64 px = 13K px).  v5's 43%-occupancy row strips
// widened the front to ~110 rows -> L2 thrash -> 1.4 GB fetch @ the ~1.9 TB/s
// scatter path -> 797 us.  v6 keeps v4's 8x8-tile serpentine XCD mapping and
// pins residency to 6 WGs/CU with a 24 KB LDS ballast, but does all work
// thread-per-pixel: no barriers, no LDS round trips, no half-wave-idle
// reduces — about half of v4's VALU instruction stream.
// ---------------------------------------------------------------------------
__global__ __launch_bounds__(64) void eval_kernel_tp8(const float* __restrict__ feat,
                                                      const float* __restrict__ offx,
                                                      const float* __restrict__ offy,
                                                      float* __restrict__ out) {
  // Residency ballast: 24 KB -> hard cap 6 workgroups/CU (160/24.6), matching
  // v4's measured ~6.5 waves/CU so the L2 gather front cannot widen.
  __shared__ float ballast[6144];

  int tid = threadIdx.x;
  int blk = blockIdx.x;
  int region = blk & 7;  // XCD round-robin residue -> fixed 256x256 region
  int slot = blk >> 3;   // 0..1023 within region
  int b = region >> 2;
  int qd = region & 3;
  int qy = (qd >> 1) << 8;
  int qx = (qd & 1) << 8;
  int tr = slot >> 5;  // 0..31
  int tc = slot & 31;
  if (tr & 1) tc = 31 - tc;  // serpentine: consecutive blocks share halo
  int h = qy + tr * 8 + (tid >> 3);
  int w = qx + tc * 8 + (tid & 7);
  int ph = h * W_ + w;
  int p = b * HW_ + ph;

  float lx = (float)w;
  float ly = (float)h;

  // keep the ballast allocated: one ds_write + one ds_read, value sunk.
  // single-wave workgroup => DS program order makes the read safe, no barrier.
  ballast[tid] = lx;
  asm volatile("" ::"v"(ballast[(tid + 1) & 63]));

  const float4* feat4 = reinterpret_cast<const float4*>(feat);

  // all 9 candidates' offsets up front (independent loads, 32B runs per row-of-8)
  const float* oxb = offx + (size_t)b * K_ * HW_ + ph;
  const float* oyb = offy + (size_t)b * K_ * HW_ + ph;
  float oxv[K_], oyv[K_];
#pragma unroll
  for (int k = 0; k < K_; ++k) {
    oxv[k] = oxb[k * HW_];
    oyv[k] = oyb[k * HW_];
  }

  // own pixel's 36 center features -> registers (contiguous, 16B aligned)
  float F[C_];
  {
    const float4* myF = feat4 + (size_t)p * 9;
#pragma unroll
    for (int i = 0; i < 9; ++i) {
      float4 v = myF[i];
      F[4 * i + 0] = v.x; F[4 * i + 1] = v.y; F[4 * i + 2] = v.z; F[4 * i + 3] = v.w;
    }
  }

  float M = -INFINITY, den = 0.f, axs = 0.f, ays = 0.f;

#pragma unroll 1
  for (int k = 0; k < K_; ++k) {
    float ox = oxv[k];
    float oy = oyv[k];
    float rx = fminf(fmaxf(lx + ox, 0.0f), 511.0f);
    float ry = fminf(fmaxf(ly + oy, 0.0f), 511.0f);
    float gx = (rx - 255.5f) / 255.5f;
    float gy = (ry - 255.5f) / 255.5f;
    float px = (gx + 1.0f) * 0.5f * 511.0f;
    float py = (gy + 1.0f) * 0.5f * 511.0f;
    int x0 = (int)floorf(px); x0 = (x0 > 510) ? 510 : x0;
    int y0 = (int)floorf(py); y0 = (y0 > 510) ? 510 : y0;
    float wx = px - (float)x0;
    float wy = py - (float)y0;
    float w00 = (1.0f - wx) * (1.0f - wy);
    float w01 = wx * (1.0f - wy);
    float w10 = (1.0f - wx) * wy;
    float w11 = wx * wy;

    // float4 base of the (y0, x0..x0+1) run; row1 is +ROWF4 (x0<=510, y0<=510)
    const float4* r0 = feat4 + (size_t)(((b * H_ + y0) * W_ + x0) * 9);

    float D[9] = {0.f, 0.f, 0.f, 0.f, 0.f, 0.f, 0.f, 0.f, 0.f};
#pragma unroll
    for (int q = 0; q < 9; ++q) {
      float4 v00 = r0[q];
      float4 v01 = r0[9 + q];
      float4 v10 = r0[ROWF4 + q];
      float4 v11 = r0[ROWF4 + 9 + q];
      float a0 = w00 * v00.x + w01 * v01.x + w10 * v10.x + w11 * v11.x;
      float a1 = w00 * v00.y + w01 * v01.y + w10 * v10.y + w11 * v11.y;
      float a2 = w00 * v00.z + w01 * v01.z + w10 * v10.z + w11 * v11.z;
      float a3 = w00 * v00.w + w01 * v01.w + w10 * v10.w + w11 * v11.w;
      int ga = q / 3;
      int f0 = 4 * (q % 3);
      D[ga]     += fabsf(F[f0 + 0]      - a0);
      D[3 + ga] += fabsf(F[12 + f0 + 0] - a0);
      D[6 + ga] += fabsf(F[24 + f0 + 0] - a0);
      D[ga]     += fabsf(F[f0 + 1]      - a1);
      D[3 + ga] += fabsf(F[12 + f0 + 1] - a1);
      D[6 + ga] += fabsf(F[24 + f0 + 1] - a1);
      D[ga]     += fabsf(F[f0 + 2]      - a2);
      D[3 + ga] += fabsf(F[12 + f0 + 2] - a2);
      D[6 + ga] += fabsf(F[24 + f0 + 2] - a2);
      D[ga]     += fabsf(F[f0 + 3]      - a3);
      D[3 + ga] += fabsf(F[12 + f0 + 3] - a3);
      D[6 + ga] += fabsf(F[24 + f0 + 3] - a3);
    }

    float mn = D[0];
#pragma unroll
    for (int j = 1; j < 9; ++j) mn = fminf(mn, D[j]);
    float xk = -(mn / 12.0f) * 1000.0f;
    float nm = fmaxf(M, xk);
    float scl = expf(M - nm);
    float ek = expf(xk - nm);
    den = den * scl + ek;
    axs = axs * scl + ox * ek;
    ays = ays * scl + oy * ek;
    M = nm;
  }

  float resx = axs / den;
  float resy = ays / den;
  out[p] = fminf(fmaxf(resx + lx, 0.0f), 511.0f) - lx;
  out[B_ * HW_ + p] = fminf(fmaxf(resy + ly, 0.0f), 511.0f) - ly;
}

// Fallback (no scratch): original channel-major layout, thread-per-pixel.
__global__ __launch_bounds__(256) void eval_kernel_n(const float* __restrict__ feat,
                                                     const float* __restrict__ offx,
                                                     const float* __restrict__ offy,
                                                     float* __restrict__ out) {
  int p = blockIdx.x * 256 + threadIdx.x;
  int ph = p & (HW_ - 1);
  int b = p >> 18;
  float F[C_];
  const float* fb = feat + (size_t)b * C_ * HW_ + ph;
#pragma unroll
  for (int c = 0; c < C_; ++c) F[c] = fb[(size_t)c * HW_];
  float lx = (float)(ph & (W_ - 1));
  float ly = (float)((ph >> 9) & (H_ - 1));
  const float* oxb = offx + (size_t)b * K_ * HW_ + ph;
  const float* oyb = offy + (size_t)b * K_ * HW_ + ph;
  float M = -INFINITY, den = 0.f, ax = 0.f, ay = 0.f;
#pragma unroll 1
  for (int k = 0; k < K_; ++k) {
    float ox = oxb[k * HW_];
    float oy = oyb[k * HW_];
    float rx = fminf(fmaxf(lx + ox, 0.0f), 511.0f);
    float ry = fminf(fmaxf(ly + oy, 0.0f), 511.0f);
    float gx = (rx - 255.5f) / 255.5f;
    float gy = (ry - 255.5f) / 255.5f;
    float px = (gx + 1.0f) * 0.5f * 511.0f;
    float py = (gy + 1.0f) * 0.5f * 511.0f;
    int x0 = (int)floorf(px); x0 = (x0 > 510) ? 510 : x0;
    int y0 = (int)floorf(py); y0 = (y0 > 510) ? 510 : y0;
    float wx = px - (float)x0;
    float wy = py - (float)y0;
    float w00 = (1.0f - wx) * (1.0f - wy);
    float w01 = wx * (1.0f - wy);
    float w10 = (1.0f - wx) * wy;
    float w11 = wx * wy;
    float D[9] = {0.f, 0.f, 0.f, 0.f, 0.f, 0.f, 0.f, 0.f, 0.f};
    const float* pl = feat + (size_t)b * C_ * HW_ + (size_t)y0 * W_ + x0;
#pragma unroll
    for (int c = 0; c < C_; ++c) {
      const float* q0 = pl + (size_t)c * HW_;
      float v00 = q0[0], v01 = q0[1];
      float v10 = q0[W_], v11 = q0[W_ + 1];
      float a = v00 * w00 + v01 * w01 + v10 * w10 + v11 * w11;
      int i = c % 12;
      int ga = c / 12;
      D[ga]     += fabsf(F[i]      - a);
      D[3 + ga] += fabsf(F[12 + i] - a);
      D[6 + ga] += fabsf(F[24 + i] - a);
    }
    float mn = D[0];
#pragma unroll
    for (int j = 1; j < 9; ++j) mn = fminf(mn, D[j]);
    float xk = -(mn / 12.0f) * 1000.0f;
    float nm = fmaxf(M, xk);
    float sc = expf(M - nm);
    float ek = expf(xk - nm);
    den = den * sc + ek;
    ax = ax * sc + ox * ek;
    ay = ay * sc + oy * ek;
    M = nm;
  }
  float resx = ax / den;
  float resy = ay / den;
  out[p] = fminf(fmaxf(resx + lx, 0.0f), 511.0f) - lx;
  out[B_ * HW_ + p] = fminf(fmaxf(resy + ly, 0.0f), 511.0f) - ly;
}

extern "C" void kernel_launch(void* const* d_in, const int* in_sizes, int n_in,
                              void* d_out, int out_size, void* d_ws, size_t ws_size,
                              hipStream_t stream) {
  const float* features = (const float*)d_in[0];
  const float* offset_x = (const float*)d_in[1];
  const float* offset_y = (const float*)d_in[2];
  float* out = (float*)d_out;

  const int npix = B_ * HW_;  // 524288
  const size_t need = (size_t)npix * C_ * sizeof(float);  // 75.5 MB

  if (ws_size >= need) {
    float* featT = (float*)d_ws;
    transpose_kernel<<<B_ * H_ * (W_ / 64), 256, 0, stream>>>(features, featT);
    eval_kernel_tp8<<<npix / 64, 64, 0, stream>>>(featT, offset_x, offset_y, out);
  } else {
    eval_kernel_n<<<npix / 256, 256, 0, stream>>>(features, offset_x, offset_y, out);
  }
}